// Round 1
// baseline (6573.507 us; speedup 1.0000x reference)
//
#include <hip/hip_runtime.h>
#include <cstdint>
#include <cstddef>

#define T_   4
#define NTOK 2048
#define D_   1024
#define EF   512
#define NE   8
#define TP   8   // (token,expert) pairs per expert-kernel tile

// ---------------- ws layout ----------------
// rp:    double[NTOK*NE]   offset 0        (131072 B)  per-token softmax(es)
// cnt:   int[NE]           offset 131072   (32 B)      per-expert pair counts
// ltok:  int[NE*NTOK]      offset 131104   (65536 B)   token id per pair
// lw:    double[NE*NTOK]   offset 196640   (131072 B)  combine weight per pair
#define WS_RP   0
#define WS_CNT  131072
#define WS_LTOK 131104
#define WS_LW   196640

// ---------------------------------------------------------------------------
// Kernel 1: routing. One block per token. LIF spikes on x (fp64, elementwise),
// exact integer per-expert spike counts -> es (exact dyadic), top-2 with
// jax tie-break (descending value, lower index first), softmax weights,
// softmax(es) for load-balance loss, append pairs to per-expert lists.
// ---------------------------------------------------------------------------
__global__ __launch_bounds__(256) void moe_routing(
    const float* __restrict__ x, const float* __restrict__ bias,
    double* __restrict__ rp, int* __restrict__ cnt,
    int* __restrict__ ltok, double* __restrict__ lw)
{
    const int n   = blockIdx.x;
    const int tid = threadIdx.x;
    __shared__ int scnt[NE];
    if (tid < NE) scnt[tid] = 0;
    __syncthreads();

    // Each thread handles d = j*256 + tid.  (d & 63) is identical for all j,
    // so all 4 features of a thread map to the same expert bin.
    int c = 0;
#pragma unroll
    for (int j = 0; j < 4; ++j) {
        const int d = j * 256 + tid;
        double v = 0.0;
#pragma unroll
        for (int t = 0; t < T_; ++t) {
            v = 0.9 * v + (double)x[((size_t)t * NTOK + n) * D_ + d];
            if (v - 1.0 >= 0.0) { ++c; v -= 1.0; }
        }
    }
    // reduce within 8-lane groups (one expert per group)
    c += __shfl_xor(c, 1);
    c += __shfl_xor(c, 2);
    c += __shfl_xor(c, 4);
    if ((tid & 7) == 0) atomicAdd(&scnt[(tid >> 3) & 7], c);
    __syncthreads();

    if (tid == 0) {
        double es[NE];
#pragma unroll
        for (int e = 0; e < NE; ++e)
            es[e] = (double)scnt[e] * (1.0 / 512.0) + (double)bias[e];  // /TEMP==1

        // top-2, jax tie-break: strictly-greater keeps earliest index
        int i0 = 0; double b0 = es[0];
        for (int e = 1; e < NE; ++e) if (es[e] > b0) { b0 = es[e]; i0 = e; }
        int i1 = -1; double b1 = -1e300;
        for (int e = 0; e < NE; ++e) if (e != i0 && es[e] > b1) { b1 = es[e]; i1 = e; }

        const double e1 = exp(b1 - b0);            // softmax over (b0,b1), b0 is max
        const double w0 = 1.0 / (1.0 + e1);
        const double w1 = e1 / (1.0 + e1);

        // softmax over all experts for the load-balance loss
        double mx = es[0];
        for (int e = 1; e < NE; ++e) mx = es[e] > mx ? es[e] : mx;
        double s = 0.0, ex[NE];
        for (int e = 0; e < NE; ++e) { ex[e] = exp(es[e] - mx); s += ex[e]; }
        for (int e = 0; e < NE; ++e) rp[(size_t)n * NE + e] = ex[e] / s;

        int s0 = atomicAdd(&cnt[i0], 1);
        ltok[i0 * NTOK + s0] = n; lw[i0 * NTOK + s0] = w0;
        int s1 = atomicAdd(&cnt[i1], 1);
        ltok[i1 * NTOK + s1] = n; lw[i1 * NTOK + s1] = w1;
    }
}

// ---------------------------------------------------------------------------
// Kernel 2: load-balance loss reduction -> out[T*NTOK*D_]
// ---------------------------------------------------------------------------
__global__ __launch_bounds__(256) void moe_finalize(
    const double* __restrict__ rp, const int* __restrict__ cnt,
    float* __restrict__ out_lb)
{
    __shared__ double red[256][NE];
    const int tid = threadIdx.x;
    double a[NE];
#pragma unroll
    for (int e = 0; e < NE; ++e) a[e] = 0.0;
    for (int n = tid; n < NTOK; n += 256)
#pragma unroll
        for (int e = 0; e < NE; ++e) a[e] += rp[(size_t)n * NE + e];
#pragma unroll
    for (int e = 0; e < NE; ++e) red[tid][e] = a[e];
    __syncthreads();
    if (tid < NE) {
        double s = 0.0;
        for (int i = 0; i < 256; ++i) s += red[i][tid];
        red[0][tid] = s;
    }
    __syncthreads();
    if (tid == 0) {
        double lb = 0.0;
#pragma unroll
        for (int e = 0; e < NE; ++e)
            lb += ((double)cnt[e] / (double)(NTOK * 2)) * (red[0][e] / (double)NTOK);
        out_lb[0] = (float)(8.0 * lb);
    }
}

// ---------------------------------------------------------------------------
// Kernel 3: expert FFN over selected (token, expert) pairs, fp64 membranes.
// Grid (256 tiles, NE experts); tile = TP pairs = 32 rows (pair*4 + t).
// 256 threads = 128 f/d lanes x 2 row-groups of 16 rows (4 pairs).
// ---------------------------------------------------------------------------
__global__ __launch_bounds__(256) void moe_expert(
    const float* __restrict__ x, const float* __restrict__ wup,
    const float* __restrict__ wdn,
    const int* __restrict__ cnt, const int* __restrict__ ltok,
    const double* __restrict__ lw, float* __restrict__ out)
{
    const int e    = blockIdx.y;
    const int tile = blockIdx.x;
    const int c    = cnt[e];
    const int base = tile * TP;
    if (base >= c) return;

    const int tid    = threadIdx.x;
    const int f_lane = tid & 127;   // also d_lane in down phase
    const int rg     = tid >> 7;    // row-group 0/1
    const int lane   = tid & 63;
    const int wavep  = (tid >> 6) & 1;

    __shared__ int    s_tok[TP];
    __shared__ double s_w[TP];
    __shared__ double xs[4 * TP][128];        // 32 KiB, fp64 x chunk
    __shared__ unsigned hmask[4 * TP][16];    // 2 KiB, hs spike bits (512 f)

    if (tid < TP) {
        const int idx = base + tid;
        if (idx < c) { s_tok[tid] = ltok[e * NTOK + idx]; s_w[tid] = lw[e * NTOK + idx]; }
        else         { s_tok[tid] = ltok[e * NTOK + base]; s_w[tid] = 0.0; }  // pad, w=0
    }
    __syncthreads();

    const float* W = wup + (size_t)e * D_ * EF;

    // ---------------- up projection + LIF -> spike bitmask ----------------
    for (int fc = 0; fc < 2; ++fc) {
        double a[16][2];
#pragma unroll
        for (int r = 0; r < 16; ++r) { a[r][0] = 0.0; a[r][1] = 0.0; }

        for (int kc = 0; kc < 8; ++kc) {
            __syncthreads();   // previous xs readers done
            for (int i = tid; i < 32 * 128; i += 256) {
                const int r = i >> 7, j = i & 127;
                const int n = s_tok[r >> 2];
                const int t = r & 3;
                xs[r][j] = (double)x[((size_t)t * NTOK + n) * D_ + kc * 128 + j];
            }
            __syncthreads();

            const float* Wk = W + (size_t)(kc * 128) * EF + fc * 256 + f_lane;
            for (int k = 0; k < 128; k += 2) {
                const double w00 = (double)Wk[0];
                const double w01 = (double)Wk[128];
                const double w10 = (double)Wk[EF];
                const double w11 = (double)Wk[EF + 128];
                Wk += 2 * EF;
#pragma unroll
                for (int r = 0; r < 16; ++r) {
                    const double2 xv = *(const double2*)&xs[rg * 16 + r][k];
                    a[r][0] = fma(xv.x, w00, a[r][0]);
                    a[r][1] = fma(xv.x, w01, a[r][1]);
                    a[r][0] = fma(xv.y, w10, a[r][0]);
                    a[r][1] = fma(xv.y, w11, a[r][1]);
                }
            }
        }
        // LIF across t (rows pl*4+t live in this thread), ballot -> bitmask
#pragma unroll
        for (int pl = 0; pl < 4; ++pl) {
#pragma unroll
            for (int fj = 0; fj < 2; ++fj) {
                double v = 0.0;
#pragma unroll
                for (int t = 0; t < 4; ++t) {
                    v = 0.9 * v + a[pl * 4 + t][fj];
                    const bool s = (v - 1.0 >= 0.0);
                    if (s) v -= 1.0;
                    const unsigned long long bal = __ballot(s);
                    if (lane == 0)
                        *(unsigned long long*)&hmask[rg * 16 + pl * 4 + t]
                                                    [fc * 8 + fj * 4 + wavep * 2] = bal;
                }
            }
        }
    }
    __syncthreads();

    // ---------------- down projection (binary) + LIF -> weighted out ------
    const float* Wd = wdn + (size_t)e * EF * D_;
    const int d_lane = f_lane;

    for (int dc = 0; dc < 4; ++dc) {
        double b[16][2];
#pragma unroll
        for (int r = 0; r < 16; ++r) { b[r][0] = 0.0; b[r][1] = 0.0; }

        for (int fw = 0; fw < 8; ++fw) {
            unsigned mlo[16], mhi[16];
#pragma unroll
            for (int r = 0; r < 16; ++r) {
                const unsigned long long m =
                    *(const unsigned long long*)&hmask[rg * 16 + r][fw * 2];
                mlo[r] = __builtin_amdgcn_readfirstlane((unsigned)m);
                mhi[r] = __builtin_amdgcn_readfirstlane((unsigned)(m >> 32));
            }
            const float* Wf = Wd + (size_t)(fw * 64) * D_ + dc * 256 + d_lane;
#pragma unroll 1
            for (int fb = 0; fb < 32; ++fb) {
                const unsigned bit = 1u << fb;
                {
                    const double dv0 = (double)Wf[0];
                    const double dv1 = (double)Wf[128];
#pragma unroll
                    for (int r = 0; r < 16; ++r)
                        if (mlo[r] & bit) { b[r][0] += dv0; b[r][1] += dv1; }
                }
                {
                    const double dv0 = (double)Wf[(size_t)32 * D_];
                    const double dv1 = (double)Wf[(size_t)32 * D_ + 128];
#pragma unroll
                    for (int r = 0; r < 16; ++r)
                        if (mhi[r] & bit) { b[r][0] += dv0; b[r][1] += dv1; }
                }
                Wf += D_;
            }
        }
        // LIF on o, scatter weighted spikes
#pragma unroll
        for (int pl = 0; pl < 4; ++pl) {
            const int pidx = rg * 4 + pl;
            const double wgt = s_w[pidx];
            const int n = s_tok[pidx];
#pragma unroll
            for (int dj = 0; dj < 2; ++dj) {
                double v = 0.0;
#pragma unroll
                for (int t = 0; t < 4; ++t) {
                    v = 0.9 * v + b[pl * 4 + t][dj];
                    if (v - 1.0 >= 0.0) {
                        v -= 1.0;
                        if (wgt != 0.0)
                            atomicAdd(&out[((size_t)t * NTOK + n) * D_ +
                                           dc * 256 + dj * 128 + d_lane],
                                      (float)wgt);
                    }
                }
            }
        }
    }
}

// ---------------------------------------------------------------------------
extern "C" void kernel_launch(void* const* d_in, const int* in_sizes, int n_in,
                              void* d_out, int out_size, void* d_ws, size_t ws_size,
                              hipStream_t stream)
{
    const float* x    = (const float*)d_in[0];
    const float* wup  = (const float*)d_in[1];
    const float* wdn  = (const float*)d_in[2];
    const float* bias = (const float*)d_in[3];
    float* out = (float*)d_out;
    char*  ws  = (char*)d_ws;

    double* rp   = (double*)(ws + WS_RP);
    int*    cnt  = (int*)(ws + WS_CNT);
    int*    ltok = (int*)(ws + WS_LTOK);
    double* lw   = (double*)(ws + WS_LW);

    hipMemsetAsync(d_out, 0, (size_t)out_size * sizeof(float), stream);
    hipMemsetAsync(cnt, 0, NE * sizeof(int), stream);

    moe_routing<<<NTOK, 256, 0, stream>>>(x, bias, rp, cnt, ltok, lw);
    moe_finalize<<<1, 256, 0, stream>>>(rp, cnt, out + (size_t)T_ * NTOK * D_);
    moe_expert<<<dim3(256, NE), 256, 0, stream>>>(x, wup, wdn, cnt, ltok, lw, out);
}

// Round 2
// 3113.582 us; speedup vs baseline: 2.1112x; 2.1112x over previous
//
#include <hip/hip_runtime.h>
#include <cstdint>
#include <cstddef>

#define T_   4
#define NTOK 2048
#define D_   1024
#define EF   512
#define NE   8
#define TP   8   // (token,expert) pairs per expert-kernel tile

// ---------------- ws layout ----------------
#define WS_RP   0        // double[NTOK*NE]
#define WS_CNT  131072   // int[NE]
#define WS_LTOK 131104   // int[NE*NTOK]
#define WS_LW   196640   // double[NE*NTOK]

// ---------------------------------------------------------------------------
// Kernel 1: routing (unchanged from R1 — verified exact, absmax 0.0)
// ---------------------------------------------------------------------------
__global__ __launch_bounds__(256) void moe_routing(
    const float* __restrict__ x, const float* __restrict__ bias,
    double* __restrict__ rp, int* __restrict__ cnt,
    int* __restrict__ ltok, double* __restrict__ lw)
{
    const int n   = blockIdx.x;
    const int tid = threadIdx.x;
    __shared__ int scnt[NE];
    if (tid < NE) scnt[tid] = 0;
    __syncthreads();

    int c = 0;
#pragma unroll
    for (int j = 0; j < 4; ++j) {
        const int d = j * 256 + tid;
        double v = 0.0;
#pragma unroll
        for (int t = 0; t < T_; ++t) {
            v = 0.9 * v + (double)x[((size_t)t * NTOK + n) * D_ + d];
            if (v - 1.0 >= 0.0) { ++c; v -= 1.0; }
        }
    }
    c += __shfl_xor(c, 1);
    c += __shfl_xor(c, 2);
    c += __shfl_xor(c, 4);
    if ((tid & 7) == 0) atomicAdd(&scnt[(tid >> 3) & 7], c);
    __syncthreads();

    if (tid == 0) {
        double es[NE];
#pragma unroll
        for (int e = 0; e < NE; ++e)
            es[e] = (double)scnt[e] * (1.0 / 512.0) + (double)bias[e];

        int i0 = 0; double b0 = es[0];
        for (int e = 1; e < NE; ++e) if (es[e] > b0) { b0 = es[e]; i0 = e; }
        int i1 = -1; double b1 = -1e300;
        for (int e = 0; e < NE; ++e) if (e != i0 && es[e] > b1) { b1 = es[e]; i1 = e; }

        const double e1 = exp(b1 - b0);
        const double w0 = 1.0 / (1.0 + e1);
        const double w1 = e1 / (1.0 + e1);

        double mx = es[0];
        for (int e = 1; e < NE; ++e) mx = es[e] > mx ? es[e] : mx;
        double s = 0.0, ex[NE];
        for (int e = 0; e < NE; ++e) { ex[e] = exp(es[e] - mx); s += ex[e]; }
        for (int e = 0; e < NE; ++e) rp[(size_t)n * NE + e] = ex[e] / s;

        int s0 = atomicAdd(&cnt[i0], 1);
        ltok[i0 * NTOK + s0] = n; lw[i0 * NTOK + s0] = w0;
        int s1 = atomicAdd(&cnt[i1], 1);
        ltok[i1 * NTOK + s1] = n; lw[i1 * NTOK + s1] = w1;
    }
}

// ---------------------------------------------------------------------------
// Kernel 2: load-balance loss (unchanged)
// ---------------------------------------------------------------------------
__global__ __launch_bounds__(256) void moe_finalize(
    const double* __restrict__ rp, const int* __restrict__ cnt,
    float* __restrict__ out_lb)
{
    __shared__ double red[256][NE];
    const int tid = threadIdx.x;
    double a[NE];
#pragma unroll
    for (int e = 0; e < NE; ++e) a[e] = 0.0;
    for (int n = tid; n < NTOK; n += 256)
#pragma unroll
        for (int e = 0; e < NE; ++e) a[e] += rp[(size_t)n * NE + e];
#pragma unroll
    for (int e = 0; e < NE; ++e) red[tid][e] = a[e];
    __syncthreads();
    if (tid < NE) {
        double s = 0.0;
        for (int i = 0; i < 256; ++i) s += red[i][tid];
        red[0][tid] = s;
    }
    __syncthreads();
    if (tid == 0) {
        double lb = 0.0;
#pragma unroll
        for (int e = 0; e < NE; ++e)
            lb += ((double)cnt[e] / (double)(NTOK * 2)) * (red[0][e] / (double)NTOK);
        out_lb[0] = (float)(8.0 * lb);
    }
}

// ---------------------------------------------------------------------------
// Kernel 3: expert FFN. 512 threads = 128 f/d lanes x 4 row-groups of 8 rows.
// Flat grid: gid -> (e = gid&7, tile = gid>>3) so working blocks spread over
// all CUs. Explicit load rotation pipelines L2 latency.
// ---------------------------------------------------------------------------
__global__ __launch_bounds__(512, 4) void moe_expert(
    const float* __restrict__ x, const float* __restrict__ wup,
    const float* __restrict__ wdn,
    const int* __restrict__ cnt, const int* __restrict__ ltok,
    const double* __restrict__ lw, float* __restrict__ out)
{
    const int gid  = blockIdx.x;
    const int e    = gid & 7;
    const int tile = gid >> 3;
    const int c    = cnt[e];
    const int base = tile * TP;
    if (base >= c) return;

    const int tid    = threadIdx.x;
    const int f_lane = tid & 127;        // also d_lane in down phase
    const int rg     = tid >> 7;         // row-group 0..3 (8 rows each)
    const int lane   = tid & 63;
    const int wavep  = (tid >> 6) & 1;

    __shared__ int    s_tok[TP];
    __shared__ double s_w[TP];
    __shared__ double xs[4 * TP][128];     // 32 KiB fp64 x chunk
    __shared__ unsigned hmask[4 * TP][16]; // 2 KiB spike bitmasks (512 f)

    if (tid < TP) {
        const int idx = base + tid;
        if (idx < c) { s_tok[tid] = ltok[e * NTOK + idx]; s_w[tid] = lw[e * NTOK + idx]; }
        else         { s_tok[tid] = ltok[e * NTOK + base]; s_w[tid] = 0.0; }
    }
    __syncthreads();

    const float* W = wup + (size_t)e * D_ * EF;

    // ---------------- up projection + LIF -> spike bitmasks ----------------
    for (int fc = 0; fc < 2; ++fc) {
        double a[8][2];
#pragma unroll
        for (int r = 0; r < 8; ++r) { a[r][0] = 0.0; a[r][1] = 0.0; }

        for (int kc = 0; kc < 8; ++kc) {
            __syncthreads();   // previous xs readers done
#pragma unroll
            for (int p = 0; p < 2; ++p) {
                const int r = (tid >> 5) + p * 16;
                const int j = (tid & 31) * 4;
                const int n = s_tok[r >> 2];
                const int t = r & 3;
                const float4 xv = *(const float4*)&x[((size_t)t * NTOK + n) * D_ + kc * 128 + j];
                double2 lo; lo.x = (double)xv.x; lo.y = (double)xv.y;
                double2 hi; hi.x = (double)xv.z; hi.y = (double)xv.w;
                *(double2*)&xs[r][j]     = lo;
                *(double2*)&xs[r][j + 2] = hi;
            }
            __syncthreads();

            const float* Wk = W + (size_t)(kc * 128) * EF + fc * 256 + f_lane;
            float c00 = Wk[0], c01 = Wk[128], c10 = Wk[EF], c11 = Wk[EF + 128];
#pragma unroll 1
            for (int g = 0; g < 64; ++g) {
                const float* Wn = (g < 63) ? (Wk + 2 * EF) : Wk;   // rotate prefetch
                const float n00 = Wn[0],  n01 = Wn[128];
                const float n10 = Wn[EF], n11 = Wn[EF + 128];
                const double w00 = (double)c00, w01 = (double)c01;
                const double w10 = (double)c10, w11 = (double)c11;
                const int k = g * 2;
#pragma unroll
                for (int r = 0; r < 8; ++r) {
                    const double2 xv = *(const double2*)&xs[rg * 8 + r][k];
                    a[r][0] = fma(xv.x, w00, a[r][0]);
                    a[r][1] = fma(xv.x, w01, a[r][1]);
                    a[r][0] = fma(xv.y, w10, a[r][0]);
                    a[r][1] = fma(xv.y, w11, a[r][1]);
                }
                c00 = n00; c01 = n01; c10 = n10; c11 = n11;
                Wk = Wn;
            }
        }
        // LIF across t; ballot -> bitmask. rows rg*8 + pl*4 + t (pl = pair-in-rg)
#pragma unroll
        for (int pl = 0; pl < 2; ++pl) {
#pragma unroll
            for (int fj = 0; fj < 2; ++fj) {
                double v = 0.0;
#pragma unroll
                for (int t = 0; t < 4; ++t) {
                    v = 0.9 * v + a[pl * 4 + t][fj];
                    const bool s = (v - 1.0 >= 0.0);
                    if (s) v -= 1.0;
                    const unsigned long long bal = __ballot(s);
                    if (lane == 0)
                        *(unsigned long long*)&hmask[rg * 8 + pl * 4 + t]
                                                    [fc * 8 + fj * 4 + wavep * 2] = bal;
                }
            }
        }
    }
    __syncthreads();

    // ---------------- down projection (binary) + LIF -> weighted out ------
    const float* Wd = wdn + (size_t)e * EF * D_;
    const int d_lane = f_lane;

    for (int dc = 0; dc < 4; ++dc) {
        double b[8][2];
#pragma unroll
        for (int r = 0; r < 8; ++r) { b[r][0] = 0.0; b[r][1] = 0.0; }

        for (int fw = 0; fw < 8; ++fw) {
            unsigned mlo[8], mhi[8];
#pragma unroll
            for (int r = 0; r < 8; ++r) {
                const unsigned long long m =
                    *(const unsigned long long*)&hmask[rg * 8 + r][fw * 2];
                mlo[r] = __builtin_amdgcn_readfirstlane((unsigned)m);
                mhi[r] = __builtin_amdgcn_readfirstlane((unsigned)(m >> 32));
            }
            const float* Wf = Wd + (size_t)(fw * 64) * D_ + dc * 256 + d_lane;
            float c0 = Wf[0], c1 = Wf[128];
            float c2 = Wf[(size_t)32 * D_], c3 = Wf[(size_t)32 * D_ + 128];
#pragma unroll 1
            for (int fb = 0; fb < 32; ++fb) {
                const float* Wn = (fb < 31) ? (Wf + D_) : Wf;      // rotate prefetch
                const float n0 = Wn[0], n1 = Wn[128];
                const float n2 = Wn[(size_t)32 * D_], n3 = Wn[(size_t)32 * D_ + 128];
                const unsigned bit = 1u << fb;
                const double d0 = (double)c0, d1 = (double)c1;
                const double d2 = (double)c2, d3 = (double)c3;
#pragma unroll
                for (int r = 0; r < 8; ++r) {
                    if (mlo[r] & bit) { b[r][0] += d0; b[r][1] += d1; }
                    if (mhi[r] & bit) { b[r][0] += d2; b[r][1] += d3; }
                }
                c0 = n0; c1 = n1; c2 = n2; c3 = n3;
                Wf = Wn;
            }
        }
        // LIF on o, scatter weighted spikes
#pragma unroll
        for (int pl = 0; pl < 2; ++pl) {
            const int pidx = rg * 2 + pl;
            const double wgt = s_w[pidx];
            const int n = s_tok[pidx];
#pragma unroll
            for (int dj = 0; dj < 2; ++dj) {
                double v = 0.0;
#pragma unroll
                for (int t = 0; t < 4; ++t) {
                    v = 0.9 * v + b[pl * 4 + t][dj];
                    if (v - 1.0 >= 0.0) {
                        v -= 1.0;
                        if (wgt != 0.0)
                            atomicAdd(&out[((size_t)t * NTOK + n) * D_ +
                                           dc * 256 + dj * 128 + d_lane],
                                      (float)wgt);
                    }
                }
            }
        }
    }
}

// ---------------------------------------------------------------------------
extern "C" void kernel_launch(void* const* d_in, const int* in_sizes, int n_in,
                              void* d_out, int out_size, void* d_ws, size_t ws_size,
                              hipStream_t stream)
{
    const float* x    = (const float*)d_in[0];
    const float* wup  = (const float*)d_in[1];
    const float* wdn  = (const float*)d_in[2];
    const float* bias = (const float*)d_in[3];
    float* out = (float*)d_out;
    char*  ws  = (char*)d_ws;

    double* rp   = (double*)(ws + WS_RP);
    int*    cnt  = (int*)(ws + WS_CNT);
    int*    ltok = (int*)(ws + WS_LTOK);
    double* lw   = (double*)(ws + WS_LW);

    hipMemsetAsync(d_out, 0, (size_t)out_size * sizeof(float), stream);
    hipMemsetAsync(cnt, 0, NE * sizeof(int), stream);

    moe_routing<<<NTOK, 256, 0, stream>>>(x, bias, rp, cnt, ltok, lw);
    moe_finalize<<<1, 256, 0, stream>>>(rp, cnt, out + (size_t)T_ * NTOK * D_);
    moe_expert<<<NE * 256, 512, 0, stream>>>(x, wup, wdn, cnt, ltok, lw, out);
}

// Round 3
// 2293.200 us; speedup vs baseline: 2.8665x; 1.3577x over previous
//
#include <hip/hip_runtime.h>
#include <cstdint>
#include <cstddef>

#define T_   4
#define NTOK 2048
#define D_   1024
#define EF   512
#define NE   8
#define TP   4   // (token,expert) pairs per expert-kernel tile

// ---------------- ws layout ----------------
#define WS_RP   0        // double[NTOK*NE]
#define WS_CNT  131072   // int[NE]
#define WS_LTOK 131104   // int[NE*NTOK]
#define WS_LW   196640   // double[NE*NTOK]

// ---------------------------------------------------------------------------
// Kernel 1: routing (unchanged — verified exact, absmax 0.0)
// ---------------------------------------------------------------------------
__global__ __launch_bounds__(256) void moe_routing(
    const float* __restrict__ x, const float* __restrict__ bias,
    double* __restrict__ rp, int* __restrict__ cnt,
    int* __restrict__ ltok, double* __restrict__ lw)
{
    const int n   = blockIdx.x;
    const int tid = threadIdx.x;
    __shared__ int scnt[NE];
    if (tid < NE) scnt[tid] = 0;
    __syncthreads();

    int c = 0;
#pragma unroll
    for (int j = 0; j < 4; ++j) {
        const int d = j * 256 + tid;
        double v = 0.0;
#pragma unroll
        for (int t = 0; t < T_; ++t) {
            v = 0.9 * v + (double)x[((size_t)t * NTOK + n) * D_ + d];
            if (v - 1.0 >= 0.0) { ++c; v -= 1.0; }
        }
    }
    c += __shfl_xor(c, 1);
    c += __shfl_xor(c, 2);
    c += __shfl_xor(c, 4);
    if ((tid & 7) == 0) atomicAdd(&scnt[(tid >> 3) & 7], c);
    __syncthreads();

    if (tid == 0) {
        double es[NE];
#pragma unroll
        for (int e = 0; e < NE; ++e)
            es[e] = (double)scnt[e] * (1.0 / 512.0) + (double)bias[e];

        int i0 = 0; double b0 = es[0];
        for (int e = 1; e < NE; ++e) if (es[e] > b0) { b0 = es[e]; i0 = e; }
        int i1 = -1; double b1 = -1e300;
        for (int e = 0; e < NE; ++e) if (e != i0 && es[e] > b1) { b1 = es[e]; i1 = e; }

        const double e1 = exp(b1 - b0);
        const double w0 = 1.0 / (1.0 + e1);
        const double w1 = e1 / (1.0 + e1);

        double mx = es[0];
        for (int e = 1; e < NE; ++e) mx = es[e] > mx ? es[e] : mx;
        double s = 0.0, ex[NE];
        for (int e = 0; e < NE; ++e) { ex[e] = exp(es[e] - mx); s += ex[e]; }
        for (int e = 0; e < NE; ++e) rp[(size_t)n * NE + e] = ex[e] / s;

        int s0 = atomicAdd(&cnt[i0], 1);
        ltok[i0 * NTOK + s0] = n; lw[i0 * NTOK + s0] = w0;
        int s1 = atomicAdd(&cnt[i1], 1);
        ltok[i1 * NTOK + s1] = n; lw[i1 * NTOK + s1] = w1;
    }
}

// ---------------------------------------------------------------------------
// Kernel 2: load-balance loss (unchanged)
// ---------------------------------------------------------------------------
__global__ __launch_bounds__(256) void moe_finalize(
    const double* __restrict__ rp, const int* __restrict__ cnt,
    float* __restrict__ out_lb)
{
    __shared__ double red[256][NE];
    const int tid = threadIdx.x;
    double a[NE];
#pragma unroll
    for (int e = 0; e < NE; ++e) a[e] = 0.0;
    for (int n = tid; n < NTOK; n += 256)
#pragma unroll
        for (int e = 0; e < NE; ++e) a[e] += rp[(size_t)n * NE + e];
#pragma unroll
    for (int e = 0; e < NE; ++e) red[tid][e] = a[e];
    __syncthreads();
    if (tid < NE) {
        double s = 0.0;
        for (int i = 0; i < 256; ++i) s += red[i][tid];
        red[0][tid] = s;
    }
    __syncthreads();
    if (tid == 0) {
        double lb = 0.0;
#pragma unroll
        for (int e = 0; e < NE; ++e)
            lb += ((double)cnt[e] / (double)(NTOK * 2)) * (red[0][e] / (double)NTOK);
        out_lb[0] = (float)(8.0 * lb);
    }
}

// ---------------------------------------------------------------------------
// Kernel 3: expert FFN. TP=4 pairs/block, 256 threads = 128 f/d lanes x
// 2 row-groups of 8 rows. Each lane accumulates 4 f-columns (f_lane + c*128),
// so x is staged once per k-chunk and the whole EF=512 is covered in one pass.
// ~1032 working blocks -> 16 waves/CU resident.
// ---------------------------------------------------------------------------
__global__ __launch_bounds__(256, 4) void moe_expert(
    const float* __restrict__ x, const float* __restrict__ wup,
    const float* __restrict__ wdn,
    const int* __restrict__ cnt, const int* __restrict__ ltok,
    const double* __restrict__ lw, float* __restrict__ out)
{
    const int gid  = blockIdx.x;
    const int e    = gid & 7;
    const int tile = gid >> 3;
    const int c    = cnt[e];
    const int base = tile * TP;
    if (base >= c) return;

    const int tid    = threadIdx.x;
    const int f_lane = tid & 127;        // also d_lane in down phase
    const int rg     = tid >> 7;         // row-group 0..1 (8 rows each)
    const int lane   = tid & 63;
    const int wavep  = (tid >> 6) & 1;

    __shared__ int    s_tok[TP];
    __shared__ double s_w[TP];
    __shared__ double xs[4 * TP][128];      // 16 rows x 128 dbl = 16 KiB
    __shared__ unsigned hmask[4 * TP][16];  // 1 KiB spike bitmasks (512 f)

    if (tid < TP) {
        const int idx = base + tid;
        if (idx < c) { s_tok[tid] = ltok[e * NTOK + idx]; s_w[tid] = lw[e * NTOK + idx]; }
        else         { s_tok[tid] = ltok[e * NTOK + base]; s_w[tid] = 0.0; }
    }
    __syncthreads();

    const float* W = wup + (size_t)e * D_ * EF;

    // ---------------- up projection + LIF -> spike bitmasks ----------------
    double a[8][4];
#pragma unroll
    for (int r = 0; r < 8; ++r)
#pragma unroll
        for (int q = 0; q < 4; ++q) a[r][q] = 0.0;

    for (int kc = 0; kc < 8; ++kc) {
        __syncthreads();   // previous xs readers done
#pragma unroll
        for (int p = 0; p < 2; ++p) {
            const int r = (tid >> 5) + p * 8;
            const int m = tid & 31;
            const int n = s_tok[r >> 2];
            const int t = r & 3;
            const float4 xv = *(const float4*)&x[((size_t)t * NTOK + n) * D_ + kc * 128 + 4 * m];
            double2 lo; lo.x = (double)xv.x; lo.y = (double)xv.y;
            double2 hi; hi.x = (double)xv.z; hi.y = (double)xv.w;
            *(double2*)&xs[r][4 * m]     = lo;
            *(double2*)&xs[r][4 * m + 2] = hi;
        }
        __syncthreads();

        // 8 weight floats per g: rows 2g,2g+1 x cols (f_lane + c*128).
        // Byte offsets {0,512,...,3584} all fold into load immediates.
        const float* Wk = W + (size_t)(kc * 128) * EF + f_lane;
        float c0 = Wk[0],   c1 = Wk[128], c2 = Wk[256], c3 = Wk[384];
        float c4 = Wk[512], c5 = Wk[640], c6 = Wk[768], c7 = Wk[896];
#pragma unroll 1
        for (int g = 0; g < 64; ++g) {
            const float* Wn = (g < 63) ? (Wk + 2 * EF) : Wk;   // rotate prefetch
            const float n0 = Wn[0],   n1 = Wn[128], n2 = Wn[256], n3 = Wn[384];
            const float n4 = Wn[512], n5 = Wn[640], n6 = Wn[768], n7 = Wn[896];
            const double w00 = (double)c0, w01 = (double)c1;
            const double w02 = (double)c2, w03 = (double)c3;
            const double w10 = (double)c4, w11 = (double)c5;
            const double w12 = (double)c6, w13 = (double)c7;
            const int k = g * 2;
#pragma unroll
            for (int r = 0; r < 8; ++r) {
                const double2 xv = *(const double2*)&xs[rg * 8 + r][k];
                a[r][0] = fma(xv.x, w00, a[r][0]); a[r][0] = fma(xv.y, w10, a[r][0]);
                a[r][1] = fma(xv.x, w01, a[r][1]); a[r][1] = fma(xv.y, w11, a[r][1]);
                a[r][2] = fma(xv.x, w02, a[r][2]); a[r][2] = fma(xv.y, w12, a[r][2]);
                a[r][3] = fma(xv.x, w03, a[r][3]); a[r][3] = fma(xv.y, w13, a[r][3]);
            }
            c0 = n0; c1 = n1; c2 = n2; c3 = n3;
            c4 = n4; c5 = n5; c6 = n6; c7 = n7;
            Wk = Wn;
        }
    }

    // LIF across t; ballot -> bitmask. rows rg*8 + pl*4 + t
#pragma unroll
    for (int pl = 0; pl < 2; ++pl) {
#pragma unroll
        for (int q = 0; q < 4; ++q) {
            double v = 0.0;
#pragma unroll
            for (int t = 0; t < 4; ++t) {
                v = 0.9 * v + a[pl * 4 + t][q];
                const bool s = (v - 1.0 >= 0.0);
                if (s) v -= 1.0;
                const unsigned long long bal = __ballot(s);
                if (lane == 0)
                    *(unsigned long long*)&hmask[rg * 8 + pl * 4 + t]
                                                [q * 4 + wavep * 2] = bal;
            }
        }
    }
    __syncthreads();

    // ---------------- down projection (binary) + LIF -> weighted out ------
    const float* Wd = wdn + (size_t)e * EF * D_;
    const int d_lane = f_lane;

    for (int dc = 0; dc < 4; ++dc) {
        double b[8][2];
#pragma unroll
        for (int r = 0; r < 8; ++r) { b[r][0] = 0.0; b[r][1] = 0.0; }

        for (int fw = 0; fw < 8; ++fw) {
            unsigned mlo[8], mhi[8];
#pragma unroll
            for (int r = 0; r < 8; ++r) {
                const unsigned long long m =
                    *(const unsigned long long*)&hmask[rg * 8 + r][fw * 2];
                mlo[r] = __builtin_amdgcn_readfirstlane((unsigned)m);
                mhi[r] = __builtin_amdgcn_readfirstlane((unsigned)(m >> 32));
            }
            const float* Wf = Wd + (size_t)(fw * 64) * D_ + dc * 256 + d_lane;
            float c0 = Wf[0], c1 = Wf[128];
            float c2 = Wf[(size_t)32 * D_], c3 = Wf[(size_t)32 * D_ + 128];
#pragma unroll 1
            for (int fb = 0; fb < 32; ++fb) {
                const float* Wn = (fb < 31) ? (Wf + D_) : Wf;      // rotate prefetch
                const float n0 = Wn[0], n1 = Wn[128];
                const float n2 = Wn[(size_t)32 * D_], n3 = Wn[(size_t)32 * D_ + 128];
                const unsigned bit = 1u << fb;
                const double d0 = (double)c0, d1 = (double)c1;
                const double d2 = (double)c2, d3 = (double)c3;
#pragma unroll
                for (int r = 0; r < 8; ++r) {
                    if (mlo[r] & bit) { b[r][0] += d0; b[r][1] += d1; }
                    if (mhi[r] & bit) { b[r][0] += d2; b[r][1] += d3; }
                }
                c0 = n0; c1 = n1; c2 = n2; c3 = n3;
                Wf = Wn;
            }
        }
        // LIF on o, scatter weighted spikes
#pragma unroll
        for (int pl = 0; pl < 2; ++pl) {
            const int pidx = rg * 2 + pl;
            const double wgt = s_w[pidx];
            const int n = s_tok[pidx];
#pragma unroll
            for (int dj = 0; dj < 2; ++dj) {
                double v = 0.0;
#pragma unroll
                for (int t = 0; t < 4; ++t) {
                    v = 0.9 * v + b[pl * 4 + t][dj];
                    if (v - 1.0 >= 0.0) {
                        v -= 1.0;
                        if (wgt != 0.0)
                            atomicAdd(&out[((size_t)t * NTOK + n) * D_ +
                                           dc * 256 + dj * 128 + d_lane],
                                      (float)wgt);
                    }
                }
            }
        }
    }
}

// ---------------------------------------------------------------------------
extern "C" void kernel_launch(void* const* d_in, const int* in_sizes, int n_in,
                              void* d_out, int out_size, void* d_ws, size_t ws_size,
                              hipStream_t stream)
{
    const float* x    = (const float*)d_in[0];
    const float* wup  = (const float*)d_in[1];
    const float* wdn  = (const float*)d_in[2];
    const float* bias = (const float*)d_in[3];
    float* out = (float*)d_out;
    char*  ws  = (char*)d_ws;

    double* rp   = (double*)(ws + WS_RP);
    int*    cnt  = (int*)(ws + WS_CNT);
    int*    ltok = (int*)(ws + WS_LTOK);
    double* lw   = (double*)(ws + WS_LW);

    hipMemsetAsync(d_out, 0, (size_t)out_size * sizeof(float), stream);
    hipMemsetAsync(cnt, 0, NE * sizeof(int), stream);

    moe_routing<<<NTOK, 256, 0, stream>>>(x, bias, rp, cnt, ltok, lw);
    moe_finalize<<<1, 256, 0, stream>>>(rp, cnt, out + (size_t)T_ * NTOK * D_);
    moe_expert<<<NE * 512, 256, 0, stream>>>(x, wup, wdn, cnt, ltok, lw, out);
}

// Round 5
// 1136.720 us; speedup vs baseline: 5.7829x; 2.0174x over previous
//
#include <hip/hip_runtime.h>
#include <cstdint>
#include <cstddef>

#define T_   4
#define NTOK 2048
#define D_   1024
#define EF   512
#define NE   8
#define TP   4   // (token,expert) pairs per expert tile -> 16 rows (pair*4+t)

typedef __attribute__((ext_vector_type(4))) double d4;

// ---------------- ws layout ----------------
#define WS_RP   0        // double[NTOK*NE]
#define WS_CNT  131072   // int[NE]
#define WS_LTOK 131104   // int[NE*NTOK]
#define WS_LW   196640   // double[NE*NTOK]

// ---------------------------------------------------------------------------
// Kernel 1: routing (unchanged — verified exact, absmax 0.0)
// ---------------------------------------------------------------------------
__global__ __launch_bounds__(256) void moe_routing(
    const float* __restrict__ x, const float* __restrict__ bias,
    double* __restrict__ rp, int* __restrict__ cnt,
    int* __restrict__ ltok, double* __restrict__ lw)
{
    const int n   = blockIdx.x;
    const int tid = threadIdx.x;
    __shared__ int scnt[NE];
    if (tid < NE) scnt[tid] = 0;
    __syncthreads();

    int c = 0;
#pragma unroll
    for (int j = 0; j < 4; ++j) {
        const int d = j * 256 + tid;
        double v = 0.0;
#pragma unroll
        for (int t = 0; t < T_; ++t) {
            v = 0.9 * v + (double)x[((size_t)t * NTOK + n) * D_ + d];
            if (v - 1.0 >= 0.0) { ++c; v -= 1.0; }
        }
    }
    c += __shfl_xor(c, 1);
    c += __shfl_xor(c, 2);
    c += __shfl_xor(c, 4);
    if ((tid & 7) == 0) atomicAdd(&scnt[(tid >> 3) & 7], c);
    __syncthreads();

    if (tid == 0) {
        double es[NE];
#pragma unroll
        for (int e = 0; e < NE; ++e)
            es[e] = (double)scnt[e] * (1.0 / 512.0) + (double)bias[e];

        int i0 = 0; double b0 = es[0];
        for (int e = 1; e < NE; ++e) if (es[e] > b0) { b0 = es[e]; i0 = e; }
        int i1 = -1; double b1 = -1e300;
        for (int e = 0; e < NE; ++e) if (e != i0 && es[e] > b1) { b1 = es[e]; i1 = e; }

        const double e1 = exp(b1 - b0);
        const double w0 = 1.0 / (1.0 + e1);
        const double w1 = e1 / (1.0 + e1);

        double mx = es[0];
        for (int e = 1; e < NE; ++e) mx = es[e] > mx ? es[e] : mx;
        double s = 0.0, ex[NE];
        for (int e = 0; e < NE; ++e) { ex[e] = exp(es[e] - mx); s += ex[e]; }
        for (int e = 0; e < NE; ++e) rp[(size_t)n * NE + e] = ex[e] / s;

        int s0 = atomicAdd(&cnt[i0], 1);
        ltok[i0 * NTOK + s0] = n; lw[i0 * NTOK + s0] = w0;
        int s1 = atomicAdd(&cnt[i1], 1);
        ltok[i1 * NTOK + s1] = n; lw[i1 * NTOK + s1] = w1;
    }
}

// ---------------------------------------------------------------------------
// Kernel 2: load-balance loss (unchanged)
// ---------------------------------------------------------------------------
__global__ __launch_bounds__(256) void moe_finalize(
    const double* __restrict__ rp, const int* __restrict__ cnt,
    float* __restrict__ out_lb)
{
    __shared__ double red[256][NE];
    const int tid = threadIdx.x;
    double a[NE];
#pragma unroll
    for (int e = 0; e < NE; ++e) a[e] = 0.0;
    for (int n = tid; n < NTOK; n += 256)
#pragma unroll
        for (int e = 0; e < NE; ++e) a[e] += rp[(size_t)n * NE + e];
#pragma unroll
    for (int e = 0; e < NE; ++e) red[tid][e] = a[e];
    __syncthreads();
    if (tid < NE) {
        double s = 0.0;
        for (int i = 0; i < 256; ++i) s += red[i][tid];
        red[0][tid] = s;
    }
    __syncthreads();
    if (tid == 0) {
        double lb = 0.0;
#pragma unroll
        for (int e = 0; e < NE; ++e)
            lb += ((double)cnt[e] / (double)(NTOK * 2)) * (red[0][e] / (double)NTOK);
        out_lb[0] = (float)(8.0 * lb);
    }
}

// decode probe value: fam0 (lane=16k+idx): val=96+4*idx; fam1 (lane=4*idx+k):
// val=6+16*idx. Values are exact small integers in fp64; families disjoint mod 4.
__device__ __forceinline__ int dec_idx(double val, int* fam) {
    const double r0 = (val - 96.0) * 0.25;
    const int i0 = (int)r0;
    if ((double)i0 == r0 && i0 >= 0 && i0 < 16) { *fam = 0; return i0; }
    const double r1 = (val - 6.0) * 0.0625;
    const int i1 = (int)r1;
    if ((double)i1 == r1 && i1 >= 0 && i1 < 16) { *fam = 1; return i1; }
    *fam = -1; return 0;
}

// ---------------------------------------------------------------------------
// Kernel 3: expert FFN on v_mfma_f64_16x16x4_f64 with RUNTIME-PROBED fragment
// layout. 16 rows = 4 pairs x 4 t. 256 thr = 4 waves; wave w owns 8 16-wide
// col tiles. D fragments round-trip through a per-wave LDS tile addressed by
// the probed (row,col) per register, then LIF runs in the canonical
// (pair=lane>>4, col=lane&15) arrangement. Probe failure -> scalar fallback.
// ---------------------------------------------------------------------------
__global__ __launch_bounds__(256) void moe_expert(
    const float* __restrict__ x, const float* __restrict__ wup,
    const float* __restrict__ wdn,
    const int* __restrict__ cnt, const int* __restrict__ ltok,
    const double* __restrict__ lw, float* __restrict__ out)
{
    const int gid  = blockIdx.x;
    const int e    = gid & 7;
    const int tile = gid >> 3;
    const int c    = cnt[e];
    const int base = tile * TP;
    if (base >= c) return;

    const int tid = threadIdx.x;
    const int w   = tid >> 6;     // wave 0..3
    const int l   = tid & 63;     // lane

    __shared__ int    s_tok[TP];
    __shared__ double s_w[TP];
    __shared__ unsigned short hmask16[16][34];   // spike bits: [row][f>>4] bit f&15
    __shared__ double dtile[4][16][17];          // per-wave D round-trip tile
    __shared__ int s_bad;

    if (tid < TP) {
        const int idx = base + tid;
        if (idx < c) { s_tok[tid] = ltok[e * NTOK + idx]; s_w[tid] = lw[e * NTOK + idx]; }
        else         { s_tok[tid] = ltok[e * NTOK + base]; s_w[tid] = 0.0; }
    }
    if (tid == 0) s_bad = 0;
    __syncthreads();

    // ---------------- layout probes ----------------
    const double dl = (double)l;
    const d4 zz = {0.0, 0.0, 0.0, 0.0};
    const d4 Dv = __builtin_amdgcn_mfma_f64_16x16x4f64(dl, 1.0, zz, 0, 0, 0);
    const d4 Du = __builtin_amdgcn_mfma_f64_16x16x4f64(1.0, dl, zz, 0, 0, 0);

    int vC[4], uC[4];
    int famA = -1, famB = -1, bad = 0;
#pragma unroll
    for (int r = 0; r < 4; ++r) {
        int fa, fb;
        vC[r] = dec_idx(Dv[r], &fa);
        uC[r] = dec_idx(Du[r], &fb);
        if (r == 0) { famA = fa; famB = fb; }
        bad |= (fa != famA) | (fb != famB) | (fa < 0) | (fb < 0);
    }
    // operand index assignment from decoded families
    const int vA = (famA == 0) ? (l & 15) : (l >> 2);
    const int kA = (famA == 0) ? (l >> 4) : (l & 3);
    const int uB = (famB == 0) ? (l & 15) : (l >> 2);
    const int kB = (famB == 0) ? (l >> 4) : (l & 3);

    // probe 3: verify k-pairing. sum_k 2^k * 2^(4+k) = 1360 at every (v,u).
    const d4 D3 = __builtin_amdgcn_mfma_f64_16x16x4f64(
        (double)(1 << kA), (double)(16 << kB), zz, 0, 0, 0);
#pragma unroll
    for (int r = 0; r < 4; ++r) bad |= (D3[r] != 1360.0);

    if (bad) atomicOr(&s_bad, 1);
    __syncthreads();

    if (s_bad) {
        // =================== scalar fallback (correctness only) ============
        for (int i = tid; i < 16 * 34; i += 256)
            ((unsigned short*)hmask16)[i] = 0;
        __syncthreads();

        for (int ci = tid; ci < TP * EF; ci += 256) {
            const int pair = ci >> 9;
            const int f    = ci & (EF - 1);
            const float* wc = wup + (size_t)e * D_ * EF + f;
            const float* xb = x + (size_t)s_tok[pair] * D_;
            double hh[4] = {0.0, 0.0, 0.0, 0.0};
            for (int d = 0; d < D_; ++d) {
                const double wv = (double)wc[(size_t)d * EF];
#pragma unroll
                for (int t = 0; t < 4; ++t)
                    hh[t] = fma((double)xb[(size_t)t * NTOK * D_ + d], wv, hh[t]);
            }
            double v = 0.0;
#pragma unroll
            for (int t = 0; t < 4; ++t) {
                v = 0.9 * v + hh[t];
                if (v - 1.0 >= 0.0) {
                    v -= 1.0;
                    const int s16 = (pair * 4 + t) * 34 + (f >> 4);
                    atomicOr((unsigned*)hmask16 + (s16 >> 1),
                             1u << ((f & 15) + ((s16 & 1) << 4)));
                }
            }
        }
        __syncthreads();

        for (int ci = tid; ci < TP * D_; ci += 256) {
            const int pair = ci >> 10;
            const int d    = ci & (D_ - 1);
            const double wgt2 = s_w[pair];
            const int    nn2  = s_tok[pair];
            const float* wc = wdn + (size_t)e * EF * D_ + d;
            double o[4] = {0.0, 0.0, 0.0, 0.0};
            for (int f = 0; f < EF; ++f) {
                const double wv = (double)wc[(size_t)f * D_];
#pragma unroll
                for (int t = 0; t < 4; ++t)
                    if ((hmask16[pair * 4 + t][f >> 4] >> (f & 15)) & 1)
                        o[t] += wv;
            }
            double v = 0.0;
#pragma unroll
            for (int t = 0; t < 4; ++t) {
                v = 0.9 * v + o[t];
                if (v - 1.0 >= 0.0) {
                    v -= 1.0;
                    if (wgt2 != 0.0)
                        atomicAdd(&out[((size_t)t * NTOK + nn2) * D_ + d], (float)wgt2);
                }
            }
        }
        return;
    }

    // =================== MFMA main path ====================================
    const int pp = l >> 4;      // canonical pair after round-trip
    const int cc = l & 15;      // canonical col after round-trip

    // ---------------- up projection: h = x @ Wup, K=1024 (256 steps) -------
    {
        const float* xp = x + ((size_t)(vA & 3) * NTOK + s_tok[vA >> 2]) * D_ + kA;
        const float* bp = wup + (size_t)e * D_ * EF + (size_t)kB * EF + w * 128 + uB;

        d4 acc[8];
#pragma unroll
        for (int j = 0; j < 8; ++j) acc[j] = zz;

        float aC = xp[0];
        float bC[8];
#pragma unroll
        for (int j = 0; j < 8; ++j) bC[j] = bp[j * 16];

#pragma unroll 1
        for (int kk = 0; kk < 256; ++kk) {
            const float* xn = (kk < 255) ? (xp + 4) : xp;
            const float* bn = (kk < 255) ? (bp + 4 * EF) : bp;
            const float aN = xn[0];
            float bN[8];
#pragma unroll
            for (int j = 0; j < 8; ++j) bN[j] = bn[j * 16];

            const double aD = (double)aC;
#pragma unroll
            for (int j = 0; j < 8; ++j)
                acc[j] = __builtin_amdgcn_mfma_f64_16x16x4f64(aD, (double)bC[j],
                                                              acc[j], 0, 0, 0);
            aC = aN;
#pragma unroll
            for (int j = 0; j < 8; ++j) bC[j] = bN[j];
            xp = xn; bp = bn;
        }

        // per tile: LDS round-trip (probed coords) -> canonical LIF -> bitmask
#pragma unroll
        for (int j = 0; j < 8; ++j) {
#pragma unroll
            for (int r = 0; r < 4; ++r) dtile[w][vC[r]][uC[r]] = acc[j][r];
            double v = 0.0;
#pragma unroll
            for (int t = 0; t < 4; ++t) {
                v = 0.9 * v + dtile[w][pp * 4 + t][cc];
                const bool s = (v - 1.0 >= 0.0);
                if (s) v -= 1.0;
                const unsigned long long bal = __ballot(s);
                if (l < 4)
                    hmask16[l * 4 + t][w * 8 + j] = (unsigned short)(bal >> (l * 16));
            }
        }
    }
    __syncthreads();

    // ---------------- down projection: o = spikes @ Wdn, K=512 (128 steps) --
    const double wgt = s_w[pp];
    const int    nn  = s_tok[pp];

#pragma unroll 1
    for (int p = 0; p < 2; ++p) {
        const float* dp = wdn + (size_t)e * EF * D_ + (size_t)kB * D_
                        + (p * 32 + w * 8) * 16 + uB;

        d4 acc[8];
#pragma unroll
        for (int j = 0; j < 8; ++j) acc[j] = zz;

        float bC[8];
#pragma unroll
        for (int j = 0; j < 8; ++j) bC[j] = dp[j * 16];

#pragma unroll 1
        for (int kk = 0; kk < 128; ++kk) {
            const float* dn_ = (kk < 127) ? (dp + 4 * D_) : dp;
            float bN[8];
#pragma unroll
            for (int j = 0; j < 8; ++j) bN[j] = dn_[j * 16];

            // A from spike bits: row vA, f = kk*4 + kA (exact 0.0/1.0)
            const int f = kk * 4 + kA;
            const unsigned v32 = *(const unsigned*)&hmask16[vA][(f >> 5) * 2];
            const double aD = ((v32 >> (f & 31)) & 1u) ? 1.0 : 0.0;

#pragma unroll
            for (int j = 0; j < 8; ++j)
                acc[j] = __builtin_amdgcn_mfma_f64_16x16x4f64(aD, (double)bC[j],
                                                              acc[j], 0, 0, 0);
#pragma unroll
            for (int j = 0; j < 8; ++j) bC[j] = bN[j];
            dp = dn_;
        }

        // per tile: round-trip -> canonical LIF -> weighted spike scatter
#pragma unroll
        for (int j = 0; j < 8; ++j) {
#pragma unroll
            for (int r = 0; r < 4; ++r) dtile[w][vC[r]][uC[r]] = acc[j][r];
            const int d = (p * 32 + w * 8 + j) * 16 + cc;
            double v = 0.0;
#pragma unroll
            for (int t = 0; t < 4; ++t) {
                v = 0.9 * v + dtile[w][pp * 4 + t][cc];
                if (v - 1.0 >= 0.0) {
                    v -= 1.0;
                    if (wgt != 0.0)
                        atomicAdd(&out[((size_t)t * NTOK + nn) * D_ + d], (float)wgt);
                }
            }
        }
    }
}

// ---------------------------------------------------------------------------
extern "C" void kernel_launch(void* const* d_in, const int* in_sizes, int n_in,
                              void* d_out, int out_size, void* d_ws, size_t ws_size,
                              hipStream_t stream)
{
    const float* x    = (const float*)d_in[0];
    const float* wup  = (const float*)d_in[1];
    const float* wdn  = (const float*)d_in[2];
    const float* bias = (const float*)d_in[3];
    float* out = (float*)d_out;
    char*  ws  = (char*)d_ws;

    double* rp   = (double*)(ws + WS_RP);
    int*    cnt  = (int*)(ws + WS_CNT);
    int*    ltok = (int*)(ws + WS_LTOK);
    double* lw   = (double*)(ws + WS_LW);

    hipMemsetAsync(d_out, 0, (size_t)out_size * sizeof(float), stream);
    hipMemsetAsync(cnt, 0, NE * sizeof(int), stream);

    moe_routing<<<NTOK, 256, 0, stream>>>(x, bias, rp, cnt, ltok, lw);
    moe_finalize<<<1, 256, 0, stream>>>(rp, cnt, out + (size_t)T_ * NTOK * D_);
    moe_expert<<<NE * 512, 256, 0, stream>>>(x, wup, wdn, cnt, ltok, lw, out);
}

// Round 6
// 903.280 us; speedup vs baseline: 7.2774x; 1.2584x over previous
//
#include <hip/hip_runtime.h>
#include <cstdint>
#include <cstddef>

#define T_   4
#define NTOK 2048
#define D_   1024
#define EF   512
#define NE   8
#define TP   8   // (token,expert) pairs per tile -> 32 rows = 2 MFMA row-groups

typedef __attribute__((ext_vector_type(4))) double d4;

// ---------------- ws layout ----------------
#define WS_RP    0        // double[NTOK*NE]                     131072 B
#define WS_CNT   131072   // int[NE]                             32 B
#define WS_LTOK  131104   // int[NE*NTOK]                        65536 B
#define WS_LW    196640   // double[NE*NTOK]                     131072 B
#define WS_GMASK 327712   // ushort[NE*2048*4][32]  spike bits   4 MiB

// ---------------------------------------------------------------------------
// Kernel 1: routing (unchanged — verified exact, absmax 0.0)
// ---------------------------------------------------------------------------
__global__ __launch_bounds__(256) void moe_routing(
    const float* __restrict__ x, const float* __restrict__ bias,
    double* __restrict__ rp, int* __restrict__ cnt,
    int* __restrict__ ltok, double* __restrict__ lw)
{
    const int n   = blockIdx.x;
    const int tid = threadIdx.x;
    __shared__ int scnt[NE];
    if (tid < NE) scnt[tid] = 0;
    __syncthreads();

    int c = 0;
#pragma unroll
    for (int j = 0; j < 4; ++j) {
        const int d = j * 256 + tid;
        double v = 0.0;
#pragma unroll
        for (int t = 0; t < T_; ++t) {
            v = 0.9 * v + (double)x[((size_t)t * NTOK + n) * D_ + d];
            if (v - 1.0 >= 0.0) { ++c; v -= 1.0; }
        }
    }
    c += __shfl_xor(c, 1);
    c += __shfl_xor(c, 2);
    c += __shfl_xor(c, 4);
    if ((tid & 7) == 0) atomicAdd(&scnt[(tid >> 3) & 7], c);
    __syncthreads();

    if (tid == 0) {
        double es[NE];
#pragma unroll
        for (int e = 0; e < NE; ++e)
            es[e] = (double)scnt[e] * (1.0 / 512.0) + (double)bias[e];

        int i0 = 0; double b0 = es[0];
        for (int e = 1; e < NE; ++e) if (es[e] > b0) { b0 = es[e]; i0 = e; }
        int i1 = -1; double b1 = -1e300;
        for (int e = 0; e < NE; ++e) if (e != i0 && es[e] > b1) { b1 = es[e]; i1 = e; }

        const double e1 = exp(b1 - b0);
        const double w0 = 1.0 / (1.0 + e1);
        const double w1 = e1 / (1.0 + e1);

        double mx = es[0];
        for (int e = 1; e < NE; ++e) mx = es[e] > mx ? es[e] : mx;
        double s = 0.0, ex[NE];
        for (int e = 0; e < NE; ++e) { ex[e] = exp(es[e] - mx); s += ex[e]; }
        for (int e = 0; e < NE; ++e) rp[(size_t)n * NE + e] = ex[e] / s;

        int s0 = atomicAdd(&cnt[i0], 1);
        ltok[i0 * NTOK + s0] = n; lw[i0 * NTOK + s0] = w0;
        int s1 = atomicAdd(&cnt[i1], 1);
        ltok[i1 * NTOK + s1] = n; lw[i1 * NTOK + s1] = w1;
    }
}

// ---------------------------------------------------------------------------
// Kernel 2: load-balance loss (unchanged)
// ---------------------------------------------------------------------------
__global__ __launch_bounds__(256) void moe_finalize(
    const double* __restrict__ rp, const int* __restrict__ cnt,
    float* __restrict__ out_lb)
{
    __shared__ double red[256][NE];
    const int tid = threadIdx.x;
    double a[NE];
#pragma unroll
    for (int e = 0; e < NE; ++e) a[e] = 0.0;
    for (int n = tid; n < NTOK; n += 256)
#pragma unroll
        for (int e = 0; e < NE; ++e) a[e] += rp[(size_t)n * NE + e];
#pragma unroll
    for (int e = 0; e < NE; ++e) red[tid][e] = a[e];
    __syncthreads();
    if (tid < NE) {
        double s = 0.0;
        for (int i = 0; i < 256; ++i) s += red[i][tid];
        red[0][tid] = s;
    }
    __syncthreads();
    if (tid == 0) {
        double lb = 0.0;
#pragma unroll
        for (int e = 0; e < NE; ++e)
            lb += ((double)cnt[e] / (double)(NTOK * 2)) * (red[0][e] / (double)NTOK);
        out_lb[0] = (float)(8.0 * lb);
    }
}

// probe decode (verified on HW in R5): fam0 lane=16k+idx -> val=96+4idx;
// fam1 lane=4idx+k -> val=6+16idx.
__device__ __forceinline__ int dec_idx(double val, int* fam) {
    const double r0 = (val - 96.0) * 0.25;
    const int i0 = (int)r0;
    if ((double)i0 == r0 && i0 >= 0 && i0 < 16) { *fam = 0; return i0; }
    const double r1 = (val - 6.0) * 0.0625;
    const int i1 = (int)r1;
    if ((double)i1 == r1 && i1 >= 0 && i1 < 16) { *fam = 1; return i1; }
    *fam = -1; return 0;
}

struct Frag {
    int vA, kA, uB, kB;   // A-row / A-k / B-col / B-k index of this lane
    int vC[4], uC[4];     // D (row,col) of acc reg r
    int bad;
};

__device__ __forceinline__ Frag probe_layout(int l) {
    Frag fr; fr.bad = 0;
    const d4 zz = {0.0, 0.0, 0.0, 0.0};
    const double dl = (double)l;
    const d4 Dv = __builtin_amdgcn_mfma_f64_16x16x4f64(dl, 1.0, zz, 0, 0, 0);
    const d4 Du = __builtin_amdgcn_mfma_f64_16x16x4f64(1.0, dl, zz, 0, 0, 0);
    int famA = -1, famB = -1;
#pragma unroll
    for (int r = 0; r < 4; ++r) {
        int fa, fb;
        fr.vC[r] = dec_idx(Dv[r], &fa);
        fr.uC[r] = dec_idx(Du[r], &fb);
        if (r == 0) { famA = fa; famB = fb; }
        fr.bad |= (fa != famA) | (fb != famB) | (fa < 0) | (fb < 0);
    }
    fr.vA = (famA == 0) ? (l & 15) : (l >> 2);
    fr.kA = (famA == 0) ? (l >> 4) : (l & 3);
    fr.uB = (famB == 0) ? (l & 15) : (l >> 2);
    fr.kB = (famB == 0) ? (l >> 4) : (l & 3);
    const d4 D3 = __builtin_amdgcn_mfma_f64_16x16x4f64(
        (double)(1 << fr.kA), (double)(16 << fr.kB), zz, 0, 0, 0);
#pragma unroll
    for (int r = 0; r < 4; ++r) fr.bad |= (D3[r] != 1360.0);
    return fr;
}

// gmask row of 32 ushorts per (e, pairIdx, t)
__device__ __forceinline__ size_t gm_row(int e, int pairIdx, int t) {
    return ((size_t)((e << 11) + pairIdx) * 4 + t) * 32;
}

// ---------------------------------------------------------------------------
// Kernel 3a: up projection h = x @ Wup + LIF -> spike bits in gmask.
// TP=8 pairs = 32 rows = 2 MFMA row-groups; every B load feeds 2 MFMAs.
// ---------------------------------------------------------------------------
__global__ __launch_bounds__(256) void moe_up(
    const float* __restrict__ x, const float* __restrict__ wup,
    const int* __restrict__ cnt, const int* __restrict__ ltok,
    unsigned short* __restrict__ gmask)
{
    const int gid  = blockIdx.x;
    const int e    = gid & 7;
    const int tile = gid >> 3;
    const int c    = cnt[e];
    const int base = tile * TP;
    if (base >= c) return;

    const int tid = threadIdx.x;
    const int w   = tid >> 6;
    const int l   = tid & 63;

    __shared__ int    s_tok[TP];
    __shared__ double dtile[4][16][17];
    __shared__ int s_bad;

    if (tid < TP) {
        const int idx = base + tid;
        s_tok[tid] = (idx < c) ? ltok[e * NTOK + idx] : ltok[e * NTOK + base];
    }
    if (tid == 0) s_bad = 0;
    __syncthreads();

    const Frag fr = probe_layout(l);
    if (fr.bad) atomicOr(&s_bad, 1);
    __syncthreads();

    if (s_bad) {
        // scalar fallback (dead in practice; probes verified on HW in R5)
        unsigned* gm32 = (unsigned*)gmask;
        for (int i = tid; i < TP * 4 * 16; i += 256) {   // zero our rows
            const int pr = i >> 6;
            gm32[(gm_row(e, base + pr, (i >> 4) & 3) >> 1) + (i & 15)] = 0u;
        }
        __syncthreads();
        for (int ci = tid; ci < TP * EF; ci += 256) {
            const int pair = ci >> 9;
            const int f    = ci & (EF - 1);
            const float* wc = wup + (size_t)e * D_ * EF + f;
            const float* xb = x + (size_t)s_tok[pair] * D_;
            double hh[4] = {0.0, 0.0, 0.0, 0.0};
            for (int d = 0; d < D_; ++d) {
                const double wv = (double)wc[(size_t)d * EF];
#pragma unroll
                for (int t = 0; t < 4; ++t)
                    hh[t] = fma((double)xb[(size_t)t * NTOK * D_ + d], wv, hh[t]);
            }
            double v = 0.0;
#pragma unroll
            for (int t = 0; t < 4; ++t) {
                v = 0.9 * v + hh[t];
                if (v - 1.0 >= 0.0) {
                    v -= 1.0;
                    atomicOr(&gm32[(gm_row(e, base + pair, t) >> 1) + (f >> 5)],
                             1u << (f & 31));
                }
            }
        }
        return;
    }

    // -------- MFMA path --------
    const float* xp0 = x + ((size_t)(fr.vA & 3) * NTOK + s_tok[fr.vA >> 2]) * D_ + fr.kA;
    const float* xp1 = x + ((size_t)(fr.vA & 3) * NTOK + s_tok[4 + (fr.vA >> 2)]) * D_ + fr.kA;
    const float* bp  = wup + (size_t)e * D_ * EF + (size_t)fr.kB * EF + w * 128 + fr.uB;

    const d4 zz = {0.0, 0.0, 0.0, 0.0};
    d4 acc0[8], acc1[8];
#pragma unroll
    for (int j = 0; j < 8; ++j) { acc0[j] = zz; acc1[j] = zz; }

#pragma unroll 4
    for (int kk = 0; kk < 256; ++kk) {
        const double aD0 = (double)xp0[0];
        const double aD1 = (double)xp1[0];
        float b[8];
#pragma unroll
        for (int j = 0; j < 8; ++j) b[j] = bp[j * 16];
#pragma unroll
        for (int j = 0; j < 8; ++j) {
            const double bD = (double)b[j];
            acc0[j] = __builtin_amdgcn_mfma_f64_16x16x4f64(aD0, bD, acc0[j], 0, 0, 0);
            acc1[j] = __builtin_amdgcn_mfma_f64_16x16x4f64(aD1, bD, acc1[j], 0, 0, 0);
        }
        xp0 += 4; xp1 += 4; bp += (size_t)4 * EF;
    }

    // epilogue: per group, per tile: LDS round-trip -> canonical LIF -> gmask
    const int pp = l >> 4;
    const int cc = l & 15;
#pragma unroll
    for (int g = 0; g < 2; ++g) {
#pragma unroll
        for (int j = 0; j < 8; ++j) {
            const d4 av = g ? acc1[j] : acc0[j];
#pragma unroll
            for (int r = 0; r < 4; ++r) dtile[w][fr.vC[r]][fr.uC[r]] = av[r];
            double v = 0.0;
#pragma unroll
            for (int t = 0; t < 4; ++t) {
                v = 0.9 * v + dtile[w][pp * 4 + t][cc];
                const bool s = (v - 1.0 >= 0.0);
                if (s) v -= 1.0;
                const unsigned long long bal = __ballot(s);
                if (l < 4)
                    gmask[gm_row(e, base + g * 4 + l, t) + (w * 8 + j)] =
                        (unsigned short)(bal >> (l * 16));
            }
        }
    }
}

// ---------------------------------------------------------------------------
// Kernel 3b: down projection o = spikes @ Wdn + LIF -> weighted scatter.
// Spike masks preloaded to LDS; 1 ds_read per 8 k-steps per row-group.
// ---------------------------------------------------------------------------
__global__ __launch_bounds__(256) void moe_down(
    const float* __restrict__ wdn,
    const int* __restrict__ cnt, const int* __restrict__ ltok,
    const double* __restrict__ lw, const unsigned short* __restrict__ gmask,
    float* __restrict__ out)
{
    const int gid  = blockIdx.x;
    const int e    = gid & 7;
    const int tile = gid >> 3;
    const int c    = cnt[e];
    const int base = tile * TP;
    if (base >= c) return;

    const int tid = threadIdx.x;
    const int w   = tid >> 6;
    const int l   = tid & 63;

    __shared__ int    s_tok[TP];
    __shared__ double s_w[TP];
    __shared__ unsigned hm[32][16];       // [pair*4+t][word] spike bits
    __shared__ double dtile[4][16][17];
    __shared__ int s_bad;

    if (tid < TP) {
        const int idx = base + tid;
        if (idx < c) { s_tok[tid] = ltok[e * NTOK + idx]; s_w[tid] = lw[e * NTOK + idx]; }
        else         { s_tok[tid] = ltok[e * NTOK + base]; s_w[tid] = 0.0; }
    }
    if (tid == 0) s_bad = 0;
    const unsigned* gm32 = (const unsigned*)gmask;
#pragma unroll
    for (int i = tid; i < 32 * 16; i += 256) {
        const int r = i >> 4, wd = i & 15;
        hm[r][wd] = gm32[(gm_row(e, base + (r >> 2), r & 3) >> 1) + wd];
    }
    __syncthreads();

    const Frag fr = probe_layout(l);
    if (fr.bad) atomicOr(&s_bad, 1);
    __syncthreads();

    if (s_bad) {
        // scalar fallback (dead in practice)
        for (int ci = tid; ci < TP * D_; ci += 256) {
            const int pair = ci >> 10;
            const int d    = ci & (D_ - 1);
            const double wgt2 = s_w[pair];
            const int    nn2  = s_tok[pair];
            const float* wc = wdn + (size_t)e * EF * D_ + d;
            double o[4] = {0.0, 0.0, 0.0, 0.0};
            for (int f = 0; f < EF; ++f) {
                const double wv = (double)wc[(size_t)f * D_];
#pragma unroll
                for (int t = 0; t < 4; ++t)
                    if ((hm[pair * 4 + t][f >> 5] >> (f & 31)) & 1) o[t] += wv;
            }
            double v = 0.0;
#pragma unroll
            for (int t = 0; t < 4; ++t) {
                v = 0.9 * v + o[t];
                if (v - 1.0 >= 0.0) {
                    v -= 1.0;
                    if (wgt2 != 0.0)
                        atomicAdd(&out[((size_t)t * NTOK + nn2) * D_ + d], (float)wgt2);
                }
            }
        }
        return;
    }

    // -------- MFMA path --------
    const d4 zz = {0.0, 0.0, 0.0, 0.0};
    const int pp = l >> 4;
    const int cc = l & 15;

#pragma unroll 1
    for (int p = 0; p < 2; ++p) {
        const float* dp = wdn + (size_t)e * EF * D_ + (size_t)fr.kB * D_
                        + p * 512 + w * 128 + fr.uB;

        d4 acc0[8], acc1[8];
#pragma unroll
        for (int j = 0; j < 8; ++j) { acc0[j] = zz; acc1[j] = zz; }

#pragma unroll 1
        for (int wd = 0; wd < 16; ++wd) {
            const unsigned m0 = hm[fr.vA][wd];
            const unsigned m1 = hm[16 + fr.vA][wd];
#pragma unroll
            for (int k2 = 0; k2 < 8; ++k2) {
                float b[8];
#pragma unroll
                for (int j = 0; j < 8; ++j) b[j] = dp[j * 16];
                const int bit = k2 * 4 + fr.kA;
                const double aD0 = ((m0 >> bit) & 1u) ? 1.0 : 0.0;
                const double aD1 = ((m1 >> bit) & 1u) ? 1.0 : 0.0;
#pragma unroll
                for (int j = 0; j < 8; ++j) {
                    const double bD = (double)b[j];
                    acc0[j] = __builtin_amdgcn_mfma_f64_16x16x4f64(aD0, bD, acc0[j], 0, 0, 0);
                    acc1[j] = __builtin_amdgcn_mfma_f64_16x16x4f64(aD1, bD, acc1[j], 0, 0, 0);
                }
                dp += (size_t)4 * D_;
            }
        }

        // epilogue: round-trip -> canonical LIF -> weighted spike scatter
#pragma unroll
        for (int g = 0; g < 2; ++g) {
            const int pair = g * 4 + pp;
            const double wgt = s_w[pair];
            const int    nn  = s_tok[pair];
#pragma unroll
            for (int j = 0; j < 8; ++j) {
                const d4 av = g ? acc1[j] : acc0[j];
#pragma unroll
                for (int r = 0; r < 4; ++r) dtile[w][fr.vC[r]][fr.uC[r]] = av[r];
                const int d = p * 512 + w * 128 + j * 16 + cc;
                double v = 0.0;
#pragma unroll
                for (int t = 0; t < 4; ++t) {
                    v = 0.9 * v + dtile[w][pp * 4 + t][cc];
                    if (v - 1.0 >= 0.0) {
                        v -= 1.0;
                        if (wgt != 0.0)
                            atomicAdd(&out[((size_t)t * NTOK + nn) * D_ + d], (float)wgt);
                    }
                }
            }
        }
    }
}

// ---------------------------------------------------------------------------
extern "C" void kernel_launch(void* const* d_in, const int* in_sizes, int n_in,
                              void* d_out, int out_size, void* d_ws, size_t ws_size,
                              hipStream_t stream)
{
    const float* x    = (const float*)d_in[0];
    const float* wup  = (const float*)d_in[1];
    const float* wdn  = (const float*)d_in[2];
    const float* bias = (const float*)d_in[3];
    float* out = (float*)d_out;
    char*  ws  = (char*)d_ws;

    double* rp   = (double*)(ws + WS_RP);
    int*    cnt  = (int*)(ws + WS_CNT);
    int*    ltok = (int*)(ws + WS_LTOK);
    double* lw   = (double*)(ws + WS_LW);
    unsigned short* gmask = (unsigned short*)(ws + WS_GMASK);

    hipMemsetAsync(d_out, 0, (size_t)out_size * sizeof(float), stream);
    hipMemsetAsync(cnt, 0, NE * sizeof(int), stream);

    moe_routing<<<NTOK, 256, 0, stream>>>(x, bias, rp, cnt, ltok, lw);
    moe_finalize<<<1, 256, 0, stream>>>(rp, cnt, out + (size_t)T_ * NTOK * D_);
    moe_up<<<NE * 256, 256, 0, stream>>>(x, wup, cnt, ltok, gmask);
    moe_down<<<NE * 256, 256, 0, stream>>>(wdn, cnt, ltok, lw, gmask, out);
}

// Round 7
// 798.800 us; speedup vs baseline: 8.2292x; 1.1308x over previous
//
#include <hip/hip_runtime.h>
#include <cstdint>
#include <cstddef>

#define T_   4
#define NTOK 2048
#define D_   1024
#define EF   512
#define NE   8
#define TP   8   // (token,expert) pairs per tile -> 32 rows = 2 MFMA row-groups

typedef __attribute__((ext_vector_type(4))) double d4;

// ---------------- ws layout ----------------
#define WS_RP    0        // double[NTOK*NE]                     131072 B
#define WS_CNT   131072   // int[NE]                             32 B
#define WS_LTOK  131104   // int[NE*NTOK]                        65536 B
#define WS_LW    196640   // double[NE*NTOK]                     131072 B
#define WS_GMASK 327712   // ushort[NE*2048*4][32]  spike bits   4 MiB

// ---------------------------------------------------------------------------
// Kernel 1: routing (unchanged — verified exact, absmax 0.0)
// ---------------------------------------------------------------------------
__global__ __launch_bounds__(256) void moe_routing(
    const float* __restrict__ x, const float* __restrict__ bias,
    double* __restrict__ rp, int* __restrict__ cnt,
    int* __restrict__ ltok, double* __restrict__ lw)
{
    const int n   = blockIdx.x;
    const int tid = threadIdx.x;
    __shared__ int scnt[NE];
    if (tid < NE) scnt[tid] = 0;
    __syncthreads();

    int c = 0;
#pragma unroll
    for (int j = 0; j < 4; ++j) {
        const int d = j * 256 + tid;
        double v = 0.0;
#pragma unroll
        for (int t = 0; t < T_; ++t) {
            v = 0.9 * v + (double)x[((size_t)t * NTOK + n) * D_ + d];
            if (v - 1.0 >= 0.0) { ++c; v -= 1.0; }
        }
    }
    c += __shfl_xor(c, 1);
    c += __shfl_xor(c, 2);
    c += __shfl_xor(c, 4);
    if ((tid & 7) == 0) atomicAdd(&scnt[(tid >> 3) & 7], c);
    __syncthreads();

    if (tid == 0) {
        double es[NE];
#pragma unroll
        for (int e = 0; e < NE; ++e)
            es[e] = (double)scnt[e] * (1.0 / 512.0) + (double)bias[e];

        int i0 = 0; double b0 = es[0];
        for (int e = 1; e < NE; ++e) if (es[e] > b0) { b0 = es[e]; i0 = e; }
        int i1 = -1; double b1 = -1e300;
        for (int e = 0; e < NE; ++e) if (e != i0 && es[e] > b1) { b1 = es[e]; i1 = e; }

        const double e1 = exp(b1 - b0);
        const double w0 = 1.0 / (1.0 + e1);
        const double w1 = e1 / (1.0 + e1);

        double mx = es[0];
        for (int e = 1; e < NE; ++e) mx = es[e] > mx ? es[e] : mx;
        double s = 0.0, ex[NE];
        for (int e = 0; e < NE; ++e) { ex[e] = exp(es[e] - mx); s += ex[e]; }
        for (int e = 0; e < NE; ++e) rp[(size_t)n * NE + e] = ex[e] / s;

        int s0 = atomicAdd(&cnt[i0], 1);
        ltok[i0 * NTOK + s0] = n; lw[i0 * NTOK + s0] = w0;
        int s1 = atomicAdd(&cnt[i1], 1);
        ltok[i1 * NTOK + s1] = n; lw[i1 * NTOK + s1] = w1;
    }
}

// ---------------------------------------------------------------------------
// Kernel 2: load-balance loss (unchanged)
// ---------------------------------------------------------------------------
__global__ __launch_bounds__(256) void moe_finalize(
    const double* __restrict__ rp, const int* __restrict__ cnt,
    float* __restrict__ out_lb)
{
    __shared__ double red[256][NE];
    const int tid = threadIdx.x;
    double a[NE];
#pragma unroll
    for (int e = 0; e < NE; ++e) a[e] = 0.0;
    for (int n = tid; n < NTOK; n += 256)
#pragma unroll
        for (int e = 0; e < NE; ++e) a[e] += rp[(size_t)n * NE + e];
#pragma unroll
    for (int e = 0; e < NE; ++e) red[tid][e] = a[e];
    __syncthreads();
    if (tid < NE) {
        double s = 0.0;
        for (int i = 0; i < 256; ++i) s += red[i][tid];
        red[0][tid] = s;
    }
    __syncthreads();
    if (tid == 0) {
        double lb = 0.0;
#pragma unroll
        for (int e = 0; e < NE; ++e)
            lb += ((double)cnt[e] / (double)(NTOK * 2)) * (red[0][e] / (double)NTOK);
        out_lb[0] = (float)(8.0 * lb);
    }
}

// probe decode (verified on HW in R5): fam0 lane=16k+idx -> val=96+4idx;
// fam1 lane=4idx+k -> val=6+16idx.
__device__ __forceinline__ int dec_idx(double val, int* fam) {
    const double r0 = (val - 96.0) * 0.25;
    const int i0 = (int)r0;
    if ((double)i0 == r0 && i0 >= 0 && i0 < 16) { *fam = 0; return i0; }
    const double r1 = (val - 6.0) * 0.0625;
    const int i1 = (int)r1;
    if ((double)i1 == r1 && i1 >= 0 && i1 < 16) { *fam = 1; return i1; }
    *fam = -1; return 0;
}

struct Frag {
    int vA, kA, uB, kB;   // A-row / A-k / B-col / B-k index of this lane
    int vC[4], uC[4];     // D (row,col) of acc reg r
    int bad;
};

__device__ __forceinline__ Frag probe_layout(int l) {
    Frag fr; fr.bad = 0;
    const d4 zz = {0.0, 0.0, 0.0, 0.0};
    const double dl = (double)l;
    const d4 Dv = __builtin_amdgcn_mfma_f64_16x16x4f64(dl, 1.0, zz, 0, 0, 0);
    const d4 Du = __builtin_amdgcn_mfma_f64_16x16x4f64(1.0, dl, zz, 0, 0, 0);
    int famA = -1, famB = -1;
#pragma unroll
    for (int r = 0; r < 4; ++r) {
        int fa, fb;
        fr.vC[r] = dec_idx(Dv[r], &fa);
        fr.uC[r] = dec_idx(Du[r], &fb);
        if (r == 0) { famA = fa; famB = fb; }
        fr.bad |= (fa != famA) | (fb != famB) | (fa < 0) | (fb < 0);
    }
    fr.vA = (famA == 0) ? (l & 15) : (l >> 2);
    fr.kA = (famA == 0) ? (l >> 4) : (l & 3);
    fr.uB = (famB == 0) ? (l & 15) : (l >> 2);
    fr.kB = (famB == 0) ? (l >> 4) : (l & 3);
    const d4 D3 = __builtin_amdgcn_mfma_f64_16x16x4f64(
        (double)(1 << fr.kA), (double)(16 << fr.kB), zz, 0, 0, 0);
#pragma unroll
    for (int r = 0; r < 4; ++r) fr.bad |= (D3[r] != 1360.0);
    return fr;
}

// gmask row of 32 ushorts per (e, pairIdx, t)
__device__ __forceinline__ size_t gm_row(int e, int pairIdx, int t) {
    return ((size_t)((e << 11) + pairIdx) * 4 + t) * 32;
}

// ---------------------------------------------------------------------------
// Kernel 3a: up projection h = x @ Wup + LIF -> spike bits in gmask.
// (unchanged from R6 — measured ~78% of roofline)
// ---------------------------------------------------------------------------
__global__ __launch_bounds__(256) void moe_up(
    const float* __restrict__ x, const float* __restrict__ wup,
    const int* __restrict__ cnt, const int* __restrict__ ltok,
    unsigned short* __restrict__ gmask)
{
    const int gid  = blockIdx.x;
    const int e    = gid & 7;
    const int tile = gid >> 3;
    const int c    = cnt[e];
    const int base = tile * TP;
    if (base >= c) return;

    const int tid = threadIdx.x;
    const int w   = tid >> 6;
    const int l   = tid & 63;

    __shared__ int    s_tok[TP];
    __shared__ double dtile[4][16][17];
    __shared__ int s_bad;

    if (tid < TP) {
        const int idx = base + tid;
        s_tok[tid] = (idx < c) ? ltok[e * NTOK + idx] : ltok[e * NTOK + base];
    }
    if (tid == 0) s_bad = 0;
    __syncthreads();

    const Frag fr = probe_layout(l);
    if (fr.bad) atomicOr(&s_bad, 1);
    __syncthreads();

    if (s_bad) {
        // scalar fallback (dead in practice; probes verified on HW in R5)
        unsigned* gm32 = (unsigned*)gmask;
        for (int i = tid; i < TP * 4 * 16; i += 256) {
            const int pr = i >> 6;
            gm32[(gm_row(e, base + pr, (i >> 4) & 3) >> 1) + (i & 15)] = 0u;
        }
        __syncthreads();
        for (int ci = tid; ci < TP * EF; ci += 256) {
            const int pair = ci >> 9;
            const int f    = ci & (EF - 1);
            const float* wc = wup + (size_t)e * D_ * EF + f;
            const float* xb = x + (size_t)s_tok[pair] * D_;
            double hh[4] = {0.0, 0.0, 0.0, 0.0};
            for (int d = 0; d < D_; ++d) {
                const double wv = (double)wc[(size_t)d * EF];
#pragma unroll
                for (int t = 0; t < 4; ++t)
                    hh[t] = fma((double)xb[(size_t)t * NTOK * D_ + d], wv, hh[t]);
            }
            double v = 0.0;
#pragma unroll
            for (int t = 0; t < 4; ++t) {
                v = 0.9 * v + hh[t];
                if (v - 1.0 >= 0.0) {
                    v -= 1.0;
                    atomicOr(&gm32[(gm_row(e, base + pair, t) >> 1) + (f >> 5)],
                             1u << (f & 31));
                }
            }
        }
        return;
    }

    // -------- MFMA path --------
    const float* xp0 = x + ((size_t)(fr.vA & 3) * NTOK + s_tok[fr.vA >> 2]) * D_ + fr.kA;
    const float* xp1 = x + ((size_t)(fr.vA & 3) * NTOK + s_tok[4 + (fr.vA >> 2)]) * D_ + fr.kA;
    const float* bp  = wup + (size_t)e * D_ * EF + (size_t)fr.kB * EF + w * 128 + fr.uB;

    const d4 zz = {0.0, 0.0, 0.0, 0.0};
    d4 acc0[8], acc1[8];
#pragma unroll
    for (int j = 0; j < 8; ++j) { acc0[j] = zz; acc1[j] = zz; }

#pragma unroll 4
    for (int kk = 0; kk < 256; ++kk) {
        const double aD0 = (double)xp0[0];
        const double aD1 = (double)xp1[0];
        float b[8];
#pragma unroll
        for (int j = 0; j < 8; ++j) b[j] = bp[j * 16];
#pragma unroll
        for (int j = 0; j < 8; ++j) {
            const double bD = (double)b[j];
            acc0[j] = __builtin_amdgcn_mfma_f64_16x16x4f64(aD0, bD, acc0[j], 0, 0, 0);
            acc1[j] = __builtin_amdgcn_mfma_f64_16x16x4f64(aD1, bD, acc1[j], 0, 0, 0);
        }
        xp0 += 4; xp1 += 4; bp += (size_t)4 * EF;
    }

    // epilogue: per group, per tile: LDS round-trip -> canonical LIF -> gmask
    const int pp = l >> 4;
    const int cc = l & 15;
#pragma unroll
    for (int g = 0; g < 2; ++g) {
#pragma unroll
        for (int j = 0; j < 8; ++j) {
            const d4 av = g ? acc1[j] : acc0[j];
#pragma unroll
            for (int r = 0; r < 4; ++r) dtile[w][fr.vC[r]][fr.uC[r]] = av[r];
            double v = 0.0;
#pragma unroll
            for (int t = 0; t < 4; ++t) {
                v = 0.9 * v + dtile[w][pp * 4 + t][cc];
                const bool s = (v - 1.0 >= 0.0);
                if (s) v -= 1.0;
                const unsigned long long bal = __ballot(s);
                if (l < 4)
                    gmask[gm_row(e, base + g * 4 + l, t) + (w * 8 + j)] =
                        (unsigned short)(bal >> (l * 16));
            }
        }
    }
}

// ---------------------------------------------------------------------------
// Kernel 3b: down projection o = spikes @ Wdn + LIF -> weighted scatter.
// p-half split across blocks (2x grid); rotate-prefetch of the 8 B floats
// hides L2 latency under the 16-MFMA batch; hm padded to kill bank conflicts.
// ---------------------------------------------------------------------------
__global__ __launch_bounds__(256) void moe_down(
    const float* __restrict__ wdn,
    const int* __restrict__ cnt, const int* __restrict__ ltok,
    const double* __restrict__ lw, const unsigned short* __restrict__ gmask,
    float* __restrict__ out)
{
    const int gid  = blockIdx.x;
    const int e    = gid & 7;
    const int p    = (gid >> 3) & 1;
    const int tile = gid >> 4;
    const int c    = cnt[e];
    const int base = tile * TP;
    if (base >= c) return;

    const int tid = threadIdx.x;
    const int w   = tid >> 6;
    const int l   = tid & 63;

    __shared__ int    s_tok[TP];
    __shared__ double s_w[TP];
    __shared__ unsigned hm[32][17];       // [pair*4+t][word] spike bits (padded)
    __shared__ double dtile[4][16][17];
    __shared__ int s_bad;

    if (tid < TP) {
        const int idx = base + tid;
        if (idx < c) { s_tok[tid] = ltok[e * NTOK + idx]; s_w[tid] = lw[e * NTOK + idx]; }
        else         { s_tok[tid] = ltok[e * NTOK + base]; s_w[tid] = 0.0; }
    }
    if (tid == 0) s_bad = 0;
    const unsigned* gm32 = (const unsigned*)gmask;
#pragma unroll
    for (int i = tid; i < 32 * 16; i += 256) {
        const int r = i >> 4, wd = i & 15;
        hm[r][wd] = gm32[(gm_row(e, base + (r >> 2), r & 3) >> 1) + wd];
    }
    __syncthreads();

    const Frag fr = probe_layout(l);
    if (fr.bad) atomicOr(&s_bad, 1);
    __syncthreads();

    if (s_bad) {
        // scalar fallback (dead in practice) — this block's d-half only
        for (int ci = tid; ci < TP * 512; ci += 256) {
            const int pair = ci >> 9;
            const int d    = p * 512 + (ci & 511);
            const double wgt2 = s_w[pair];
            const int    nn2  = s_tok[pair];
            const float* wc = wdn + (size_t)e * EF * D_ + d;
            double o[4] = {0.0, 0.0, 0.0, 0.0};
            for (int f = 0; f < EF; ++f) {
                const double wv = (double)wc[(size_t)f * D_];
#pragma unroll
                for (int t = 0; t < 4; ++t)
                    if ((hm[pair * 4 + t][f >> 5] >> (f & 31)) & 1) o[t] += wv;
            }
            double v = 0.0;
#pragma unroll
            for (int t = 0; t < 4; ++t) {
                v = 0.9 * v + o[t];
                if (v - 1.0 >= 0.0) {
                    v -= 1.0;
                    if (wgt2 != 0.0)
                        atomicAdd(&out[((size_t)t * NTOK + nn2) * D_ + d], (float)wgt2);
                }
            }
        }
        return;
    }

    // -------- MFMA path (single p-half) --------
    const d4 zz = {0.0, 0.0, 0.0, 0.0};
    const int pp = l >> 4;
    const int cc = l & 15;

    const float* dp = wdn + (size_t)e * EF * D_ + (size_t)fr.kB * D_
                    + p * 512 + w * 128 + fr.uB;

    d4 acc0[8], acc1[8];
#pragma unroll
    for (int j = 0; j < 8; ++j) { acc0[j] = zz; acc1[j] = zz; }

    float bC[8];
#pragma unroll
    for (int j = 0; j < 8; ++j) bC[j] = dp[j * 16];
    unsigned m0 = hm[fr.vA][0];
    unsigned m1 = hm[16 + fr.vA][0];

#pragma unroll 1
    for (int wd = 0; wd < 16; ++wd) {
        const unsigned cm0 = m0, cm1 = m1;
        const int nw = (wd < 15) ? (wd + 1) : wd;
        m0 = hm[fr.vA][nw];              // prefetch next word's masks
        m1 = hm[16 + fr.vA][nw];
#pragma unroll
        for (int k2 = 0; k2 < 8; ++k2) {
            const bool last = (wd == 15) && (k2 == 7);
            const float* dn_ = last ? dp : (dp + (size_t)4 * D_);
            float bN[8];
#pragma unroll
            for (int j = 0; j < 8; ++j) bN[j] = dn_[j * 16];   // prefetch next kk

            const int bit = k2 * 4 + fr.kA;
            const double aD0 = ((cm0 >> bit) & 1u) ? 1.0 : 0.0;
            const double aD1 = ((cm1 >> bit) & 1u) ? 1.0 : 0.0;
#pragma unroll
            for (int j = 0; j < 8; ++j) {
                const double bD = (double)bC[j];
                acc0[j] = __builtin_amdgcn_mfma_f64_16x16x4f64(aD0, bD, acc0[j], 0, 0, 0);
                acc1[j] = __builtin_amdgcn_mfma_f64_16x16x4f64(aD1, bD, acc1[j], 0, 0, 0);
            }
#pragma unroll
            for (int j = 0; j < 8; ++j) bC[j] = bN[j];
            dp = dn_;
        }
    }

    // epilogue: round-trip -> canonical LIF -> weighted spike scatter
#pragma unroll
    for (int g = 0; g < 2; ++g) {
        const int pair = g * 4 + pp;
        const double wgt = s_w[pair];
        const int    nn  = s_tok[pair];
#pragma unroll
        for (int j = 0; j < 8; ++j) {
            const d4 av = g ? acc1[j] : acc0[j];
#pragma unroll
            for (int r = 0; r < 4; ++r) dtile[w][fr.vC[r]][fr.uC[r]] = av[r];
            const int d = p * 512 + w * 128 + j * 16 + cc;
            double v = 0.0;
#pragma unroll
            for (int t = 0; t < 4; ++t) {
                v = 0.9 * v + dtile[w][pp * 4 + t][cc];
                if (v - 1.0 >= 0.0) {
                    v -= 1.0;
                    if (wgt != 0.0)
                        atomicAdd(&out[((size_t)t * NTOK + nn) * D_ + d], (float)wgt);
                }
            }
        }
    }
}

// ---------------------------------------------------------------------------
extern "C" void kernel_launch(void* const* d_in, const int* in_sizes, int n_in,
                              void* d_out, int out_size, void* d_ws, size_t ws_size,
                              hipStream_t stream)
{
    const float* x    = (const float*)d_in[0];
    const float* wup  = (const float*)d_in[1];
    const float* wdn  = (const float*)d_in[2];
    const float* bias = (const float*)d_in[3];
    float* out = (float*)d_out;
    char*  ws  = (char*)d_ws;

    double* rp   = (double*)(ws + WS_RP);
    int*    cnt  = (int*)(ws + WS_CNT);
    int*    ltok = (int*)(ws + WS_LTOK);
    double* lw   = (double*)(ws + WS_LW);
    unsigned short* gmask = (unsigned short*)(ws + WS_GMASK);

    hipMemsetAsync(d_out, 0, (size_t)out_size * sizeof(float), stream);
    hipMemsetAsync(cnt, 0, NE * sizeof(int), stream);

    moe_routing<<<NTOK, 256, 0, stream>>>(x, bias, rp, cnt, ltok, lw);
    moe_finalize<<<1, 256, 0, stream>>>(rp, cnt, out + (size_t)T_ * NTOK * D_);
    moe_up<<<NE * 256, 256, 0, stream>>>(x, wup, cnt, ltok, gmask);
    moe_down<<<NE * 512, 256, 0, stream>>>(wdn, cnt, ltok, lw, gmask, out);
}